// Round 3
// baseline (188.665 us; speedup 1.0000x reference)
//
#include <hip/hip_runtime.h>
#include <stdint.h>

#define ALPHA 0.2f
#define NEG_BIG -9000000000000000.0f

typedef __attribute__((ext_vector_type(8))) short bf16x8;
typedef __attribute__((ext_vector_type(8))) unsigned short u16x8;
typedef __attribute__((ext_vector_type(4))) float f32x4;

__device__ __forceinline__ unsigned short f2bf(float f) {
    unsigned int u = __float_as_uint(f);
    u += 0x7fffu + ((u >> 16) & 1u);   // RNE
    return (unsigned short)(u >> 16);
}
__device__ __forceinline__ float bf2f(unsigned short h) {
    return __uint_as_float(((unsigned int)h) << 16);
}

__device__ __forceinline__ void gload_lds16(const void* g, void* l) {
    __builtin_amdgcn_global_load_lds(
        (const __attribute__((address_space(1))) unsigned int*)g,
        (__attribute__((address_space(3))) unsigned int*)l, 16, 0, 0);
}

// ---------------------------------------------------------------------------
// Wt[o*256 + k] = W[k*256 + o]   (fp32, tiny)
// ---------------------------------------------------------------------------
__global__ void wt_kernel(const float* __restrict__ W, float* __restrict__ Wt) {
    int o = blockIdx.x, k = threadIdx.x;
    Wt[o * 256 + k] = W[k * 256 + o];
}

// ---------------------------------------------------------------------------
// C[M,N] = A[M,K] * Bt[N,K]^T.  A,Bt fp32 in HBM; converted to bf16 at
// fragment load; fp32 MFMA accum; C stored bf16.
// 128x128 tile, BK=32, 256 threads. fp32 tiles in LDS (16 KB each).
// ---------------------------------------------------------------------------
__global__ __launch_bounds__(256) void gemm_f32in(
    const float* __restrict__ A,
    const float* __restrict__ Bt,
    unsigned short* __restrict__ C,
    int M, int N, int K,
    long long sA, long long sB, long long sC)
{
    __shared__ __align__(16) float As[128 * 32];
    __shared__ __align__(16) float Bs[128 * 32];

    const int tid = threadIdx.x;
    const int w = tid >> 6;
    const int l = tid & 63;
    const int q = l >> 4;
    const int ml = l & 15;
    const int wm = (w >> 1) * 64;
    const int wn = (w & 1) * 64;

    const int m0 = blockIdx.y * 128;
    const int n0 = blockIdx.x * 128;
    const float* Ab = A + (size_t)blockIdx.z * sA;
    const float* Bb = Bt + (size_t)blockIdx.z * sB;
    unsigned short* Cb = C + (size_t)blockIdx.z * sC;

    f32x4 acc[4][4];
    for (int i = 0; i < 4; ++i)
        for (int j = 0; j < 4; ++j) {
            f32x4 z = {0.f, 0.f, 0.f, 0.f};
            acc[i][j] = z;
        }

    for (int k0 = 0; k0 < K; k0 += 32) {
        // Stage 128x32 fp32 tiles: 16384 B each, 16 B chunks -> 1024 chunks,
        // 4 rounds x 256 threads. Wave-uniform LDS base per instruction.
        for (int c = 0; c < 4; ++c) {
            const int cb = c * 256 + (w << 6);      // wave-uniform chunk base
            const int chunk = cb + l;
            const int r  = chunk >> 3;              // row (8 chunks per 32-f row)
            const int co = (chunk & 7) << 2;        // float offset in row
            gload_lds16(Ab + (size_t)(m0 + r) * K + k0 + co, As + cb * 4);
            gload_lds16(Bb + (size_t)(n0 + r) * K + k0 + co, Bs + cb * 4);
        }
        __syncthreads();

        bf16x8 aF[4], bF[4];
        for (int mt = 0; mt < 4; ++mt) {
            const float* ap = As + (wm + mt * 16 + ml) * 32 + q * 8;
#pragma unroll
            for (int u = 0; u < 8; ++u) aF[mt][u] = (short)f2bf(ap[u]);
        }
        for (int nt = 0; nt < 4; ++nt) {
            const float* bp = Bs + (wn + nt * 16 + ml) * 32 + q * 8;
#pragma unroll
            for (int u = 0; u < 8; ++u) bF[nt][u] = (short)f2bf(bp[u]);
        }
        for (int mt = 0; mt < 4; ++mt)
            for (int nt = 0; nt < 4; ++nt)
                acc[mt][nt] = __builtin_amdgcn_mfma_f32_16x16x32_bf16(
                    aF[mt], bF[nt], acc[mt][nt], 0, 0, 0);
        __syncthreads();
    }

    // D layout: col=lane&15, row=(lane>>4)*4+reg
    for (int mt = 0; mt < 4; ++mt)
        for (int nt = 0; nt < 4; ++nt) {
            const int gn = n0 + wn + nt * 16 + ml;
            for (int r = 0; r < 4; ++r) {
                const int gm = m0 + wm + mt * 16 + q * 4 + r;
                Cb[(size_t)gm * N + gn] = f2bf(acc[mt][nt][r]);
            }
        }
}

// ---------------------------------------------------------------------------
// el[b,i] = sum_o h[b,i,o]*a_l[o]; er likewise. h_t (bf16) is (b, o, i).
// a is fp32 (512).
// ---------------------------------------------------------------------------
__global__ __launch_bounds__(256) void eler_kernel(
    const unsigned short* __restrict__ h_t,
    const float* __restrict__ a,
    float* __restrict__ el, float* __restrict__ er)
{
    const int gi = blockIdx.x * 256 + threadIdx.x;
    const int b = gi >> 10, ii = gi & 1023;
    const unsigned short* hb = h_t + ((size_t)b * 256) * 1024 + ii;
    float sl = 0.f, sr = 0.f;
#pragma unroll 4
    for (int o = 0; o < 256; ++o) {
        const float v = bf2f(hb[(size_t)o * 1024]);
        sl += v * a[o];
        sr += v * a[256 + o];
    }
    el[gi] = sl;
    er[gi] = sr;
}

// ---------------------------------------------------------------------------
// Fused masked-softmax + PV. One block = batch b x 64 q-rows.
// Phase A: one coalesced sweep of adj rows -> c_i = m_i + log(sum_i); pack
//          adjacency bits as nibbles in LDS.
// Phase B: j-loop (step 32): rebuild P-tile (64x32 bf16) from nibbles+el/er,
//          stage h-chunk (256x32 bf16) via global_load_lds, MFMA accumulate.
// Output fp32 (b, i, o).
// ---------------------------------------------------------------------------
__global__ __launch_bounds__(256) void fused_attn(
    const int* __restrict__ adj,
    const float* __restrict__ el,
    const float* __restrict__ er,
    const unsigned short* __restrict__ h_t,
    float* __restrict__ out)
{
    __shared__ float er_s[1024];
    __shared__ float el_s[64];
    __shared__ float c_s[64];
    __shared__ unsigned char nib[64][256];
    __shared__ __align__(16) unsigned short Hs[256 * 32];
    __shared__ __align__(16) unsigned short Ps[64 * 32];

    const int tid = threadIdx.x;
    const int w = tid >> 6, l = tid & 63;
    const int q = l >> 4, ml = l & 15;
    const int b = blockIdx.y;
    const int i0 = blockIdx.x * 64;

    *(float4*)(er_s + tid * 4) = *(const float4*)(er + b * 1024 + tid * 4);
    if (tid < 64) el_s[tid] = el[b * 1024 + i0 + tid];
    __syncthreads();

    // Phase A: wave w handles rows w*16 .. w*16+15 (one row per full wave)
    for (int rr = 0; rr < 16; ++rr) {
        const int row = w * 16 + rr;
        const int* arow = adj + (size_t)(b * 1024 + i0 + row) * 1024;
        const float eli = el_s[row];
        float ev[16];
        float m = -3.0e38f;
#pragma unroll
        for (int it = 0; it < 4; ++it) {
            const int j = it * 256 + l * 4;
            const int4 av = *(const int4*)(arow + j);
            float e0 = eli + er_s[j + 0]; e0 = e0 > 0.f ? e0 : ALPHA * e0; e0 = av.x > 0 ? e0 : NEG_BIG;
            float e1 = eli + er_s[j + 1]; e1 = e1 > 0.f ? e1 : ALPHA * e1; e1 = av.y > 0 ? e1 : NEG_BIG;
            float e2 = eli + er_s[j + 2]; e2 = e2 > 0.f ? e2 : ALPHA * e2; e2 = av.z > 0 ? e2 : NEG_BIG;
            float e3 = eli + er_s[j + 3]; e3 = e3 > 0.f ? e3 : ALPHA * e3; e3 = av.w > 0 ? e3 : NEG_BIG;
            ev[it * 4 + 0] = e0; ev[it * 4 + 1] = e1;
            ev[it * 4 + 2] = e2; ev[it * 4 + 3] = e3;
            m = fmaxf(m, fmaxf(fmaxf(e0, e1), fmaxf(e2, e3)));
            nib[row][it * 64 + l] =
                (unsigned char)((av.x > 0) | ((av.y > 0) << 1) |
                                ((av.z > 0) << 2) | ((av.w > 0) << 3));
        }
#pragma unroll
        for (int off = 32; off >= 1; off >>= 1) m = fmaxf(m, __shfl_xor(m, off));
        float s = 0.f;
#pragma unroll
        for (int u = 0; u < 16; ++u) s += __expf(ev[u] - m);
#pragma unroll
        for (int off = 32; off >= 1; off >>= 1) s += __shfl_xor(s, off);
        if (l == 0) c_s[row] = m + __logf(s);
    }
    __syncthreads();

    // Phase B
    const int ib = tid >> 2;           // P-row this thread rebuilds (0..63)
    const int js = (tid & 3) * 8;      // j-offset within 32-chunk
    const float eli_b = el_s[ib];
    const float ci = c_s[ib];

    f32x4 acc[4][4];
    for (int i = 0; i < 4; ++i)
        for (int j = 0; j < 4; ++j) {
            f32x4 z = {0.f, 0.f, 0.f, 0.f};
            acc[i][j] = z;
        }

    const unsigned short* hb = h_t + (size_t)b * 262144;

    for (int j0 = 0; j0 < 1024; j0 += 32) {
        // stage Hs: rows o=0..255, cols j0..j0+31 (16 KB)
        for (int c = 0; c < 4; ++c) {
            const int cb = c * 256 + (w << 6);
            const int chunk = cb + l;
            const int r  = chunk >> 2;
            const int co = (chunk & 3) << 3;
            gload_lds16(hb + (size_t)r * 1024 + j0 + co, Hs + cb * 8);
        }
        // rebuild P-tile while loads fly (no Hs dependence)
        {
            const unsigned byte_i = (unsigned)(j0 + js) >> 2;
            const unsigned v0 = nib[ib][byte_i];
            const unsigned v1 = nib[ib][byte_i + 1];
            const unsigned v = v0 | (v1 << 4);   // bit u <-> j0+js+u
            u16x8 pvv;
#pragma unroll
            for (int u = 0; u < 8; ++u) {
                float e = eli_b + er_s[j0 + js + u];
                e = e > 0.f ? e : ALPHA * e;
                const float p = ((v >> u) & 1u) ? __expf(e - ci) : 0.f;
                pvv[u] = f2bf(p);
            }
            *(u16x8*)(Ps + ib * 32 + js) = pvv;
        }
        __syncthreads();

        bf16x8 aF[4], bF[4];
        for (int mt = 0; mt < 4; ++mt)
            aF[mt] = *(const bf16x8*)(Ps + (mt * 16 + ml) * 32 + q * 8);
        for (int nt = 0; nt < 4; ++nt)
            bF[nt] = *(const bf16x8*)(Hs + ((w << 6) + nt * 16 + ml) * 32 + q * 8);
        for (int mt = 0; mt < 4; ++mt)
            for (int nt = 0; nt < 4; ++nt)
                acc[mt][nt] = __builtin_amdgcn_mfma_f32_16x16x32_bf16(
                    aF[mt], bF[nt], acc[mt][nt], 0, 0, 0);
        __syncthreads();
    }

    // Epilogue: out (b, i, o) fp32; D layout col=lane&15, row=(lane>>4)*4+reg
    float* ob = out + (size_t)b * 262144;
    for (int mt = 0; mt < 4; ++mt)
        for (int nt = 0; nt < 4; ++nt) {
            const int gn = (w << 6) + nt * 16 + ml;
            for (int r = 0; r < 4; ++r) {
                const int gm = i0 + mt * 16 + q * 4 + r;
                ob[(size_t)gm * 256 + gn] = acc[mt][nt][r];
            }
        }
}

// ---------------------------------------------------------------------------
// Workspace (~8.8 MB):
//   Wt  (fp32) @ 0       : 262144
//   h_t (bf16) @ 262144  : 8388608   (16 x 256 x 1024)
//   el  (f32)  @ 8650752 : 65536
//   er  (f32)  @ 8716288 : 65536
// ---------------------------------------------------------------------------
extern "C" void kernel_launch(void* const* d_in, const int* in_sizes, int n_in,
                              void* d_out, int out_size, void* d_ws, size_t ws_size,
                              hipStream_t stream) {
    const float* x   = (const float*)d_in[0];   // (16,1024,256) fp32
    const int*   adj = (const int*)d_in[1];     // (16,1024,1024) int32
    const float* W   = (const float*)d_in[2];   // (256,256) fp32
    const float* a   = (const float*)d_in[3];   // (512,1) fp32
    float* out = (float*)d_out;                 // (16,1024,256) fp32

    char* ws = (char*)d_ws;
    float* Wt           = (float*)(ws);
    unsigned short* h_t = (unsigned short*)(ws + 262144);
    float* el           = (float*)(ws + 8650752);
    float* er           = (float*)(ws + 8716288);

    wt_kernel<<<dim3(256), dim3(256), 0, stream>>>(W, Wt);

    // h^T[b] (256x1024) = Wt (256x256, fp32) x x[b]^T (fp32), bf16 out
    gemm_f32in<<<dim3(8, 2, 16), dim3(256), 0, stream>>>(
        Wt, x, h_t, 256, 1024, 256, 0LL, 1024LL * 256, 256LL * 1024);

    eler_kernel<<<dim3(64), dim3(256), 0, stream>>>(h_t, a, el, er);

    fused_attn<<<dim3(16, 16), dim3(256), 0, stream>>>(adj, el, er, h_t, out);
}

// Round 4
// 163.613 us; speedup vs baseline: 1.1531x; 1.1531x over previous
//
#include <hip/hip_runtime.h>
#include <stdint.h>

#define ALPHA 0.2f
#define NEG_BIG -9000000000000000.0f

typedef __attribute__((ext_vector_type(8))) short bf16x8;
typedef __attribute__((ext_vector_type(8))) unsigned short u16x8;
typedef __attribute__((ext_vector_type(4))) float f32x4;

__device__ __forceinline__ unsigned short f2bf(float f) {
    unsigned int u = __float_as_uint(f);
    u += 0x7fffu + ((u >> 16) & 1u);   // RNE
    return (unsigned short)(u >> 16);
}

__device__ __forceinline__ void gload_lds16(const void* g, void* l) {
    __builtin_amdgcn_global_load_lds(
        (const __attribute__((address_space(1))) unsigned int*)g,
        (__attribute__((address_space(3))) unsigned int*)l, 16, 0, 0);
}

// ---------------------------------------------------------------------------
// Blocks 0..255: Wt[o*256+k] = W[k*256+o] (fp32 transpose).
// Block 256:     wa[k] = sum_o W[k][o]*a[o]; wa[256+k] likewise with a_r.
// ---------------------------------------------------------------------------
__global__ void wt_wa_kernel(const float* __restrict__ W,
                             const float* __restrict__ a,
                             float* __restrict__ Wt,
                             float* __restrict__ wa) {
    const int t = threadIdx.x;
    if (blockIdx.x < 256) {
        const int o = blockIdx.x;
        Wt[o * 256 + t] = W[t * 256 + o];
    } else {
        float sl = 0.f, sr = 0.f;
        const float* wr = W + t * 256;
        for (int o = 0; o < 256; ++o) {
            const float wv = wr[o];
            sl += wv * a[o];
            sr += wv * a[256 + o];
        }
        wa[t] = sl;
        wa[256 + t] = sr;
    }
}

// ---------------------------------------------------------------------------
// el[r] = dot(x[r,:], wa_l), er[r] = dot(x[r,:], wa_r).  One wave per row.
// ---------------------------------------------------------------------------
__global__ __launch_bounds__(256) void eler2_kernel(
    const float* __restrict__ x, const float* __restrict__ wa,
    float* __restrict__ el, float* __restrict__ er)
{
    const int w = threadIdx.x >> 6, l = threadIdx.x & 63;
    const int r = blockIdx.x * 4 + w;       // 0..16383
    const float4 xv = *(const float4*)(x + (size_t)r * 256 + l * 4);
    const float4 al = *(const float4*)(wa + l * 4);
    const float4 ar = *(const float4*)(wa + 256 + l * 4);
    float sl = xv.x * al.x + xv.y * al.y + xv.z * al.z + xv.w * al.w;
    float sr = xv.x * ar.x + xv.y * ar.y + xv.z * ar.z + xv.w * ar.w;
#pragma unroll
    for (int off = 32; off >= 1; off >>= 1) {
        sl += __shfl_xor(sl, off);
        sr += __shfl_xor(sr, off);
    }
    if (l == 0) { el[r] = sl; er[r] = sr; }
}

// ---------------------------------------------------------------------------
// C[M,N] = A[M,K]*Bt[N,K]^T, fp32 in HBM, bf16 MFMA, bf16 out. (round-3 proven)
// ---------------------------------------------------------------------------
__global__ __launch_bounds__(256) void gemm_f32in(
    const float* __restrict__ A,
    const float* __restrict__ Bt,
    unsigned short* __restrict__ C,
    int M, int N, int K,
    long long sA, long long sB, long long sC)
{
    __shared__ __align__(16) float As[128 * 32];
    __shared__ __align__(16) float Bs[128 * 32];

    const int tid = threadIdx.x;
    const int w = tid >> 6;
    const int l = tid & 63;
    const int q = l >> 4;
    const int ml = l & 15;
    const int wm = (w >> 1) * 64;
    const int wn = (w & 1) * 64;

    const int m0 = blockIdx.y * 128;
    const int n0 = blockIdx.x * 128;
    const float* Ab = A + (size_t)blockIdx.z * sA;
    const float* Bb = Bt + (size_t)blockIdx.z * sB;
    unsigned short* Cb = C + (size_t)blockIdx.z * sC;

    f32x4 acc[4][4];
    for (int i = 0; i < 4; ++i)
        for (int j = 0; j < 4; ++j) {
            f32x4 z = {0.f, 0.f, 0.f, 0.f};
            acc[i][j] = z;
        }

    for (int k0 = 0; k0 < K; k0 += 32) {
        for (int c = 0; c < 4; ++c) {
            const int cb = c * 256 + (w << 6);
            const int chunk = cb + l;
            const int r  = chunk >> 3;
            const int co = (chunk & 7) << 2;
            gload_lds16(Ab + (size_t)(m0 + r) * K + k0 + co, As + cb * 4);
            gload_lds16(Bb + (size_t)(n0 + r) * K + k0 + co, Bs + cb * 4);
        }
        __syncthreads();

        bf16x8 aF[4], bF[4];
        for (int mt = 0; mt < 4; ++mt) {
            const float* ap = As + (wm + mt * 16 + ml) * 32 + q * 8;
#pragma unroll
            for (int u = 0; u < 8; ++u) aF[mt][u] = (short)f2bf(ap[u]);
        }
        for (int nt = 0; nt < 4; ++nt) {
            const float* bp = Bs + (wn + nt * 16 + ml) * 32 + q * 8;
#pragma unroll
            for (int u = 0; u < 8; ++u) bF[nt][u] = (short)f2bf(bp[u]);
        }
        for (int mt = 0; mt < 4; ++mt)
            for (int nt = 0; nt < 4; ++nt)
                acc[mt][nt] = __builtin_amdgcn_mfma_f32_16x16x32_bf16(
                    aF[mt], bF[nt], acc[mt][nt], 0, 0, 0);
        __syncthreads();
    }

    for (int mt = 0; mt < 4; ++mt)
        for (int nt = 0; nt < 4; ++nt) {
            const int gn = n0 + wn + nt * 16 + ml;
            for (int r = 0; r < 4; ++r) {
                const int gm = m0 + wm + mt * 16 + q * 4 + r;
                Cb[(size_t)gm * N + gn] = f2bf(acc[mt][nt][r]);
            }
        }
}

// ---------------------------------------------------------------------------
// Mask pre-pass. One wave per row, 4 waves/block, 4096 blocks.
// Reads adj row coalesced once -> c[row] = m + log(sum exp(e-m));
// packs adjacency to pk16[row*64 + l] (bit t <-> j = 16*l + t).
// ---------------------------------------------------------------------------
__global__ __launch_bounds__(256) void mask_kernel(
    const int* __restrict__ adj,
    const float* __restrict__ el,
    const float* __restrict__ er,
    float* __restrict__ c,
    unsigned short* __restrict__ pk16)
{
    __shared__ unsigned char nibs[4][256];

    const int w = threadIdx.x >> 6, l = threadIdx.x & 63;
    const int row = blockIdx.x * 4 + w;       // 0..16383
    const int b = row >> 10;
    const int* arow = adj + (size_t)row * 1024;
    const float* erb = er + (b << 10);
    const float eli = el[row];

    float ev[16];
    float m = -3.0e38f;
#pragma unroll
    for (int it = 0; it < 4; ++it) {
        const int j = it * 256 + l * 4;
        const int4 av = *(const int4*)(arow + j);
        const float4 erv = *(const float4*)(erb + j);
        float e0 = eli + erv.x; e0 = e0 > 0.f ? e0 : ALPHA * e0; e0 = av.x > 0 ? e0 : NEG_BIG;
        float e1 = eli + erv.y; e1 = e1 > 0.f ? e1 : ALPHA * e1; e1 = av.y > 0 ? e1 : NEG_BIG;
        float e2 = eli + erv.z; e2 = e2 > 0.f ? e2 : ALPHA * e2; e2 = av.z > 0 ? e2 : NEG_BIG;
        float e3 = eli + erv.w; e3 = e3 > 0.f ? e3 : ALPHA * e3; e3 = av.w > 0 ? e3 : NEG_BIG;
        ev[it * 4 + 0] = e0; ev[it * 4 + 1] = e1;
        ev[it * 4 + 2] = e2; ev[it * 4 + 3] = e3;
        m = fmaxf(m, fmaxf(fmaxf(e0, e1), fmaxf(e2, e3)));
        nibs[w][it * 64 + l] =
            (unsigned char)((av.x > 0) | ((av.y > 0) << 1) |
                            ((av.z > 0) << 2) | ((av.w > 0) << 3));
    }
#pragma unroll
    for (int off = 32; off >= 1; off >>= 1) m = fmaxf(m, __shfl_xor(m, off));
    float s = 0.f;
#pragma unroll
    for (int u = 0; u < 16; ++u) s += __expf(ev[u] - m);
#pragma unroll
    for (int off = 32; off >= 1; off >>= 1) s += __shfl_xor(s, off);
    if (l == 0) c[row] = m + __logf(s);

    // repack nibbles -> per-lane 16-bit word covering j = 16l..16l+15
    const unsigned nr = *(const unsigned int*)(&nibs[w][l * 4]);
    const unsigned short mask16 =
        (unsigned short)((nr & 0xFu) | ((nr >> 4) & 0xF0u) |
                         ((nr >> 8) & 0xF00u) | ((nr >> 12) & 0xF000u));
    pk16[(size_t)row * 64 + l] = mask16;
}

// ---------------------------------------------------------------------------
// PV: out[b, i0..i0+31, :] = P @ h[b].  512 blocks (32 i-tiles x 16 b).
// P rebuilt on the fly from pk16 + el/er/c. h via h_t (o-major) = Bt layout.
// Wave w covers o-cols w*64..w*64+63; aF[2] m-frags, bF[4] n-frags.
// ---------------------------------------------------------------------------
__global__ __launch_bounds__(256) void pv_kernel(
    const unsigned short* __restrict__ pk16,
    const float* __restrict__ el,
    const float* __restrict__ er,
    const float* __restrict__ c,
    const unsigned short* __restrict__ h_t,
    float* __restrict__ out)
{
    __shared__ float er_s[1024];
    __shared__ __align__(16) unsigned short pk_s[32 * 64];
    __shared__ __align__(16) unsigned short Hs[256 * 32];
    __shared__ __align__(16) unsigned short Ps[32 * 40];  // stride 40: bank-safe

    const int tid = threadIdx.x;
    const int w = tid >> 6, l = tid & 63;
    const int q = l >> 4, ml = l & 15;
    const int b = blockIdx.y;
    const int i0 = blockIdx.x * 32;

    // prologue staging
    *(float4*)(er_s + tid * 4) = *(const float4*)(er + (b << 10) + tid * 4);
    *(u16x8*)(pk_s + tid * 8) =
        *(const u16x8*)(pk16 + ((size_t)(b << 10) + i0) * 64 + tid * 8);
    const int ib = tid >> 3;              // P-row this thread rebuilds (0..31)
    const int js = (tid & 7) * 4;         // j-offset within 32-chunk
    const float eli_b = el[(b << 10) + i0 + ib];
    const float ci = c[(b << 10) + i0 + ib];
    __syncthreads();

    f32x4 acc[2][4];
    for (int i = 0; i < 2; ++i)
        for (int j = 0; j < 4; ++j) {
            f32x4 z = {0.f, 0.f, 0.f, 0.f};
            acc[i][j] = z;
        }

    const unsigned short* hb = h_t + (size_t)b * 262144;

    for (int j0 = 0; j0 < 1024; j0 += 32) {
        // stage Hs: o-rows 0..255, cols j0..j0+31 (16 KB, 4 rounds x 256 thr)
        for (int cc = 0; cc < 4; ++cc) {
            const int cb = cc * 256 + (w << 6);
            const int chunk = cb + l;
            const int r  = chunk >> 2;
            const int co = (chunk & 3) << 3;
            gload_lds16(hb + (size_t)r * 1024 + j0 + co, Hs + cb * 8);
        }
        // rebuild P tile (32 x 32) while loads fly
        {
            const unsigned hw = pk_s[ib * 64 + ((j0 + js) >> 4)];
            const unsigned v = (hw >> ((j0 + js) & 15)) & 0xFu;
            ushort4 pvv;
            float e;
            e = eli_b + er_s[j0 + js + 0]; e = e > 0.f ? e : ALPHA * e;
            pvv.x = (v & 1u) ? f2bf(__expf(e - ci)) : (unsigned short)0;
            e = eli_b + er_s[j0 + js + 1]; e = e > 0.f ? e : ALPHA * e;
            pvv.y = (v & 2u) ? f2bf(__expf(e - ci)) : (unsigned short)0;
            e = eli_b + er_s[j0 + js + 2]; e = e > 0.f ? e : ALPHA * e;
            pvv.z = (v & 4u) ? f2bf(__expf(e - ci)) : (unsigned short)0;
            e = eli_b + er_s[j0 + js + 3]; e = e > 0.f ? e : ALPHA * e;
            pvv.w = (v & 8u) ? f2bf(__expf(e - ci)) : (unsigned short)0;
            *(ushort4*)(Ps + ib * 40 + js) = pvv;
        }
        __syncthreads();

        bf16x8 aF[2], bF[4];
        for (int mt = 0; mt < 2; ++mt)
            aF[mt] = *(const bf16x8*)(Ps + (mt * 16 + ml) * 40 + q * 8);
        for (int nt = 0; nt < 4; ++nt)
            bF[nt] = *(const bf16x8*)(Hs + ((w << 6) + nt * 16 + ml) * 32 + q * 8);
        for (int mt = 0; mt < 2; ++mt)
            for (int nt = 0; nt < 4; ++nt)
                acc[mt][nt] = __builtin_amdgcn_mfma_f32_16x16x32_bf16(
                    aF[mt], bF[nt], acc[mt][nt], 0, 0, 0);
        __syncthreads();
    }

    // epilogue: out (b,i,o) fp32; D layout col=lane&15, row=(lane>>4)*4+reg
    float* ob = out + (size_t)b * 262144;
    for (int mt = 0; mt < 2; ++mt)
        for (int nt = 0; nt < 4; ++nt) {
            const int gn = (w << 6) + nt * 16 + ml;
            for (int r = 0; r < 4; ++r) {
                const int gm = i0 + mt * 16 + q * 4 + r;
                ob[(size_t)gm * 256 + gn] = acc[mt][nt][r];
            }
        }
}

// ---------------------------------------------------------------------------
// Workspace (~10.44 MB):
//   Wt   (f32)  @ 0        : 262144
//   wa   (f32)  @ 262144   : 2048
//   h_t  (bf16) @ 264192   : 8388608   (16 x 256 x 1024)
//   el   (f32)  @ 8652800  : 65536
//   er   (f32)  @ 8718336  : 65536
//   c    (f32)  @ 8783872  : 65536
//   pk16 (u16)  @ 8849408  : 2097152   (16384 rows x 64 words)
// ---------------------------------------------------------------------------
extern "C" void kernel_launch(void* const* d_in, const int* in_sizes, int n_in,
                              void* d_out, int out_size, void* d_ws, size_t ws_size,
                              hipStream_t stream) {
    const float* x   = (const float*)d_in[0];   // (16,1024,256) fp32
    const int*   adj = (const int*)d_in[1];     // (16,1024,1024) int32
    const float* W   = (const float*)d_in[2];   // (256,256) fp32
    const float* a   = (const float*)d_in[3];   // (512,1) fp32
    float* out = (float*)d_out;                 // (16,1024,256) fp32

    char* ws = (char*)d_ws;
    float* Wt             = (float*)(ws);
    float* wa             = (float*)(ws + 262144);
    unsigned short* h_t   = (unsigned short*)(ws + 264192);
    float* el             = (float*)(ws + 8652800);
    float* er             = (float*)(ws + 8718336);
    float* c              = (float*)(ws + 8783872);
    unsigned short* pk16  = (unsigned short*)(ws + 8849408);

    wt_wa_kernel<<<dim3(257), dim3(256), 0, stream>>>(W, a, Wt, wa);

    eler2_kernel<<<dim3(4096), dim3(256), 0, stream>>>(x, wa, el, er);

    // h^T[b] (256x1024) = Wt (256x256) x x[b]^T, bf16 out
    gemm_f32in<<<dim3(8, 2, 16), dim3(256), 0, stream>>>(
        Wt, x, h_t, 256, 1024, 256, 0LL, 1024LL * 256, 256LL * 1024);

    mask_kernel<<<dim3(4096), dim3(256), 0, stream>>>(adj, el, er, c, pk16);

    pv_kernel<<<dim3(32, 16), dim3(256), 0, stream>>>(pk16, el, er, c, h_t, out);
}

// Round 5
// 163.013 us; speedup vs baseline: 1.1574x; 1.0037x over previous
//
#include <hip/hip_runtime.h>
#include <stdint.h>

#define ALPHA 0.2f
#define NEG_BIG -9000000000000000.0f

typedef __attribute__((ext_vector_type(8))) short bf16x8;
typedef __attribute__((ext_vector_type(8))) unsigned short u16x8;
typedef __attribute__((ext_vector_type(4))) float f32x4;

__device__ __forceinline__ unsigned short f2bf(float f) {
    unsigned int u = __float_as_uint(f);
    u += 0x7fffu + ((u >> 16) & 1u);   // RNE
    return (unsigned short)(u >> 16);
}

__device__ __forceinline__ void gload_lds16(const void* g, void* l) {
    __builtin_amdgcn_global_load_lds(
        (const __attribute__((address_space(1))) unsigned int*)g,
        (__attribute__((address_space(3))) unsigned int*)l, 16, 0, 0);
}

// ---------------------------------------------------------------------------
// Blocks 0..255: Wtbf[o*256+t] = bf16(W[t*256+o]).
// Block 256:     wa[k] = W[k,:]·a_l ; wa[256+k] = W[k,:]·a_r  (fp32).
// ---------------------------------------------------------------------------
__global__ void wt_wa_kernel(const float* __restrict__ W,
                             const float* __restrict__ a,
                             unsigned short* __restrict__ Wtbf,
                             float* __restrict__ wa) {
    const int t = threadIdx.x;
    if (blockIdx.x < 256) {
        const int o = blockIdx.x;
        Wtbf[o * 256 + t] = f2bf(W[t * 256 + o]);
    } else {
        float sl = 0.f, sr = 0.f;
        const float* wr = W + t * 256;
        for (int o = 0; o < 256; ++o) {
            const float wv = wr[o];
            sl += wv * a[o];
            sr += wv * a[256 + o];
        }
        wa[t] = sl;
        wa[256 + t] = sr;
    }
}

// ---------------------------------------------------------------------------
// One wave per row r: el[r] = x[r,:]·wa_l, er[r] = x[r,:]·wa_r,
// and xbf[r,:] = bf16(x[r,:])  (side output -> feeds gemm_bt).
// ---------------------------------------------------------------------------
__global__ __launch_bounds__(256) void eler2x_kernel(
    const float* __restrict__ x, const float* __restrict__ wa,
    float* __restrict__ el, float* __restrict__ er,
    unsigned short* __restrict__ xbf)
{
    const int w = threadIdx.x >> 6, l = threadIdx.x & 63;
    const int r = blockIdx.x * 4 + w;       // 0..16383
    const float4 xv = *(const float4*)(x + (size_t)r * 256 + l * 4);
    const float4 al = *(const float4*)(wa + l * 4);
    const float4 ar = *(const float4*)(wa + 256 + l * 4);

    ushort4 xb;
    xb.x = f2bf(xv.x); xb.y = f2bf(xv.y); xb.z = f2bf(xv.z); xb.w = f2bf(xv.w);
    *(ushort4*)(xbf + (size_t)r * 256 + l * 4) = xb;

    float sl = xv.x * al.x + xv.y * al.y + xv.z * al.z + xv.w * al.w;
    float sr = xv.x * ar.x + xv.y * ar.y + xv.z * ar.z + xv.w * ar.w;
#pragma unroll
    for (int off = 32; off >= 1; off >>= 1) {
        sl += __shfl_xor(sl, off);
        sr += __shfl_xor(sr, off);
    }
    if (l == 0) { el[r] = sl; er[r] = sr; }
}

// ---------------------------------------------------------------------------
// C[M,N] = A[M,K]*Bt[N,K]^T, all bf16, fp32 accum, bf16 out.
// m97 structure: 128x128 tile, BK=32, global_load_lds w16, ds_read_b128.
// ---------------------------------------------------------------------------
__global__ __launch_bounds__(256) void gemm_bt(
    const unsigned short* __restrict__ A,
    const unsigned short* __restrict__ Bt,
    unsigned short* __restrict__ C,
    int M, int N, int K,
    long long sA, long long sB, long long sC)
{
    __shared__ __align__(16) unsigned short As[128 * 32];
    __shared__ __align__(16) unsigned short Bs[128 * 32];

    const int tid = threadIdx.x;
    const int w = tid >> 6;
    const int l = tid & 63;
    const int q = l >> 4;
    const int ml = l & 15;
    const int wm = (w >> 1) * 64;
    const int wn = (w & 1) * 64;

    const int m0 = blockIdx.y * 128;
    const int n0 = blockIdx.x * 128;
    const unsigned short* Ab = A + (size_t)blockIdx.z * sA;
    const unsigned short* Bb = Bt + (size_t)blockIdx.z * sB;
    unsigned short* Cb = C + (size_t)blockIdx.z * sC;

    f32x4 acc[4][4];
    for (int i = 0; i < 4; ++i)
        for (int j = 0; j < 4; ++j) {
            f32x4 z = {0.f, 0.f, 0.f, 0.f};
            acc[i][j] = z;
        }

    for (int k0 = 0; k0 < K; k0 += 32) {
        // 8192 B per tile, 16 B chunks -> 512 chunks, 2 rounds x 256 thr
        for (int c = 0; c < 2; ++c) {
            const int cb = c * 256 + (w << 6);   // wave-uniform chunk base
            const int chunk = cb + l;
            const int r  = chunk >> 2;           // row (4 chunks per 64 B row)
            const int co = (chunk & 3) << 3;     // elem offset 0/8/16/24
            gload_lds16(Ab + (size_t)(m0 + r) * K + k0 + co, As + cb * 8);
            gload_lds16(Bb + (size_t)(n0 + r) * K + k0 + co, Bs + cb * 8);
        }
        __syncthreads();

        bf16x8 aF[4], bF[4];
        for (int mt = 0; mt < 4; ++mt)
            aF[mt] = *(const bf16x8*)(As + (wm + mt * 16 + ml) * 32 + q * 8);
        for (int nt = 0; nt < 4; ++nt)
            bF[nt] = *(const bf16x8*)(Bs + (wn + nt * 16 + ml) * 32 + q * 8);
        for (int mt = 0; mt < 4; ++mt)
            for (int nt = 0; nt < 4; ++nt)
                acc[mt][nt] = __builtin_amdgcn_mfma_f32_16x16x32_bf16(
                    aF[mt], bF[nt], acc[mt][nt], 0, 0, 0);
        __syncthreads();
    }

    // D layout: col=lane&15, row=(lane>>4)*4+reg
    for (int mt = 0; mt < 4; ++mt)
        for (int nt = 0; nt < 4; ++nt) {
            const int gn = n0 + wn + nt * 16 + ml;
            for (int r = 0; r < 4; ++r) {
                const int gm = m0 + wm + mt * 16 + q * 4 + r;
                Cb[(size_t)gm * N + gn] = f2bf(acc[mt][nt][r]);
            }
        }
}

// ---------------------------------------------------------------------------
// Mask pre-pass. One wave per row. c[row] = m + log(sum exp(e-m));
// adjacency packed to pk16[row*64 + l] (bit t <-> j = 16*l + t).
// ---------------------------------------------------------------------------
__global__ __launch_bounds__(256) void mask_kernel(
    const int* __restrict__ adj,
    const float* __restrict__ el,
    const float* __restrict__ er,
    float* __restrict__ c,
    unsigned short* __restrict__ pk16)
{
    __shared__ unsigned char nibs[4][256];

    const int w = threadIdx.x >> 6, l = threadIdx.x & 63;
    const int row = blockIdx.x * 4 + w;       // 0..16383
    const int b = row >> 10;
    const int* arow = adj + (size_t)row * 1024;
    const float* erb = er + (b << 10);
    const float eli = el[row];

    float ev[16];
    float m = -3.0e38f;
#pragma unroll
    for (int it = 0; it < 4; ++it) {
        const int j = it * 256 + l * 4;
        const int4 av = *(const int4*)(arow + j);
        const float4 erv = *(const float4*)(erb + j);
        float e0 = eli + erv.x; e0 = e0 > 0.f ? e0 : ALPHA * e0; e0 = av.x > 0 ? e0 : NEG_BIG;
        float e1 = eli + erv.y; e1 = e1 > 0.f ? e1 : ALPHA * e1; e1 = av.y > 0 ? e1 : NEG_BIG;
        float e2 = eli + erv.z; e2 = e2 > 0.f ? e2 : ALPHA * e2; e2 = av.z > 0 ? e2 : NEG_BIG;
        float e3 = eli + erv.w; e3 = e3 > 0.f ? e3 : ALPHA * e3; e3 = av.w > 0 ? e3 : NEG_BIG;
        ev[it * 4 + 0] = e0; ev[it * 4 + 1] = e1;
        ev[it * 4 + 2] = e2; ev[it * 4 + 3] = e3;
        m = fmaxf(m, fmaxf(fmaxf(e0, e1), fmaxf(e2, e3)));
        nibs[w][it * 64 + l] =
            (unsigned char)((av.x > 0) | ((av.y > 0) << 1) |
                            ((av.z > 0) << 2) | ((av.w > 0) << 3));
    }
#pragma unroll
    for (int off = 32; off >= 1; off >>= 1) m = fmaxf(m, __shfl_xor(m, off));
    float s = 0.f;
#pragma unroll
    for (int u = 0; u < 16; ++u) s += __expf(ev[u] - m);
#pragma unroll
    for (int off = 32; off >= 1; off >>= 1) s += __shfl_xor(s, off);
    if (l == 0) c[row] = m + __logf(s);

    const unsigned nr = *(const unsigned int*)(&nibs[w][l * 4]);
    const unsigned short mask16 =
        (unsigned short)((nr & 0xFu) | ((nr >> 4) & 0xF0u) |
                         ((nr >> 8) & 0xF00u) | ((nr >> 12) & 0xF000u));
    pk16[(size_t)row * 64 + l] = mask16;
}

// ---------------------------------------------------------------------------
// PV: out[b, i0..i0+31, :] = P @ h[b].  512 blocks (32 i-tiles x 16 b).
// P rebuilt on the fly from pk16 + el/er/c; h via h_t (o-major) = Bt layout.
// ---------------------------------------------------------------------------
__global__ __launch_bounds__(256) void pv_kernel(
    const unsigned short* __restrict__ pk16,
    const float* __restrict__ el,
    const float* __restrict__ er,
    const float* __restrict__ c,
    const unsigned short* __restrict__ h_t,
    float* __restrict__ out)
{
    __shared__ float er_s[1024];
    __shared__ __align__(16) unsigned short pk_s[32 * 64];
    __shared__ __align__(16) unsigned short Hs[256 * 32];
    __shared__ __align__(16) unsigned short Ps[32 * 40];  // stride 40: bank-safe

    const int tid = threadIdx.x;
    const int w = tid >> 6, l = tid & 63;
    const int q = l >> 4, ml = l & 15;
    const int b = blockIdx.y;
    const int i0 = blockIdx.x * 32;

    *(float4*)(er_s + tid * 4) = *(const float4*)(er + (b << 10) + tid * 4);
    *(u16x8*)(pk_s + tid * 8) =
        *(const u16x8*)(pk16 + ((size_t)(b << 10) + i0) * 64 + tid * 8);
    const int ib = tid >> 3;              // P-row this thread rebuilds (0..31)
    const int js = (tid & 7) * 4;         // j-offset within 32-chunk
    const float eli_b = el[(b << 10) + i0 + ib];
    const float ci = c[(b << 10) + i0 + ib];
    __syncthreads();

    f32x4 acc[2][4];
    for (int i = 0; i < 2; ++i)
        for (int j = 0; j < 4; ++j) {
            f32x4 z = {0.f, 0.f, 0.f, 0.f};
            acc[i][j] = z;
        }

    const unsigned short* hb = h_t + (size_t)b * 262144;

    for (int j0 = 0; j0 < 1024; j0 += 32) {
        for (int cc = 0; cc < 4; ++cc) {
            const int cb = cc * 256 + (w << 6);
            const int chunk = cb + l;
            const int r  = chunk >> 2;
            const int co = (chunk & 3) << 3;
            gload_lds16(hb + (size_t)r * 1024 + j0 + co, Hs + cb * 8);
        }
        {
            const unsigned hw = pk_s[ib * 64 + ((j0 + js) >> 4)];
            const unsigned v = (hw >> ((j0 + js) & 15)) & 0xFu;
            ushort4 pvv;
            float e;
            e = eli_b + er_s[j0 + js + 0]; e = e > 0.f ? e : ALPHA * e;
            pvv.x = (v & 1u) ? f2bf(__expf(e - ci)) : (unsigned short)0;
            e = eli_b + er_s[j0 + js + 1]; e = e > 0.f ? e : ALPHA * e;
            pvv.y = (v & 2u) ? f2bf(__expf(e - ci)) : (unsigned short)0;
            e = eli_b + er_s[j0 + js + 2]; e = e > 0.f ? e : ALPHA * e;
            pvv.z = (v & 4u) ? f2bf(__expf(e - ci)) : (unsigned short)0;
            e = eli_b + er_s[j0 + js + 3]; e = e > 0.f ? e : ALPHA * e;
            pvv.w = (v & 8u) ? f2bf(__expf(e - ci)) : (unsigned short)0;
            *(ushort4*)(Ps + ib * 40 + js) = pvv;
        }
        __syncthreads();

        bf16x8 aF[2], bF[4];
        for (int mt = 0; mt < 2; ++mt)
            aF[mt] = *(const bf16x8*)(Ps + (mt * 16 + ml) * 40 + q * 8);
        for (int nt = 0; nt < 4; ++nt)
            bF[nt] = *(const bf16x8*)(Hs + ((w << 6) + nt * 16 + ml) * 32 + q * 8);
        for (int mt = 0; mt < 2; ++mt)
            for (int nt = 0; nt < 4; ++nt)
                acc[mt][nt] = __builtin_amdgcn_mfma_f32_16x16x32_bf16(
                    aF[mt], bF[nt], acc[mt][nt], 0, 0, 0);
        __syncthreads();
    }

    float* ob = out + (size_t)b * 262144;
    for (int mt = 0; mt < 2; ++mt)
        for (int nt = 0; nt < 4; ++nt) {
            const int gn = (w << 6) + nt * 16 + ml;
            for (int r = 0; r < 4; ++r) {
                const int gm = i0 + mt * 16 + q * 4 + r;
                ob[(size_t)gm * 256 + gn] = acc[mt][nt][r];
            }
        }
}

// ---------------------------------------------------------------------------
// Workspace (~19.2 MB; ws_size ~268 MB per round-4 fill counters):
//   Wtbf (bf16) @ 0        : 131072
//   wa   (f32)  @ 131072   : 2048
//   xbf  (bf16) @ 133120   : 8388608
//   h_t  (bf16) @ 8521728  : 8388608
//   el   (f32)  @ 16910336 : 65536
//   er   (f32)  @ 16975872 : 65536
//   c    (f32)  @ 17041408 : 65536
//   pk16 (u16)  @ 17106944 : 2097152
// ---------------------------------------------------------------------------
extern "C" void kernel_launch(void* const* d_in, const int* in_sizes, int n_in,
                              void* d_out, int out_size, void* d_ws, size_t ws_size,
                              hipStream_t stream) {
    const float* x   = (const float*)d_in[0];   // (16,1024,256) fp32
    const int*   adj = (const int*)d_in[1];     // (16,1024,1024) int32
    const float* W   = (const float*)d_in[2];   // (256,256) fp32
    const float* a   = (const float*)d_in[3];   // (512,1) fp32
    float* out = (float*)d_out;                 // (16,1024,256) fp32

    char* ws = (char*)d_ws;
    unsigned short* Wtbf  = (unsigned short*)(ws);
    float* wa             = (float*)(ws + 131072);
    unsigned short* xbf   = (unsigned short*)(ws + 133120);
    unsigned short* h_t   = (unsigned short*)(ws + 8521728);
    float* el             = (float*)(ws + 16910336);
    float* er             = (float*)(ws + 16975872);
    float* c              = (float*)(ws + 17041408);
    unsigned short* pk16  = (unsigned short*)(ws + 17106944);

    wt_wa_kernel<<<dim3(257), dim3(256), 0, stream>>>(W, a, Wtbf, wa);

    eler2x_kernel<<<dim3(4096), dim3(256), 0, stream>>>(x, wa, el, er, xbf);

    // h^T[b] (256x1024) = Wtbf (256x256) x xbf[b]^T, bf16 out
    gemm_bt<<<dim3(8, 2, 16), dim3(256), 0, stream>>>(
        Wtbf, xbf, h_t, 256, 1024, 256, 0LL, 1024LL * 256, 256LL * 1024);

    mask_kernel<<<dim3(4096), dim3(256), 0, stream>>>(adj, el, er, c, pk16);

    pv_kernel<<<dim3(32, 16), dim3(256), 0, stream>>>(pk16, el, er, c, h_t, out);
}

// Round 6
// 155.125 us; speedup vs baseline: 1.2162x; 1.0509x over previous
//
#include <hip/hip_runtime.h>
#include <stdint.h>

#define ALPHA 0.2f
#define NEG_BIG -9000000000000000.0f

typedef __attribute__((ext_vector_type(8))) short bf16x8;
typedef __attribute__((ext_vector_type(8))) unsigned short u16x8;
typedef __attribute__((ext_vector_type(4))) float f32x4;

__device__ __forceinline__ unsigned short f2bf(float f) {
    unsigned int u = __float_as_uint(f);
    u += 0x7fffu + ((u >> 16) & 1u);   // RNE
    return (unsigned short)(u >> 16);
}

__device__ __forceinline__ void gload_lds16(const void* g, void* l) {
    __builtin_amdgcn_global_load_lds(
        (const __attribute__((address_space(1))) unsigned int*)g,
        (__attribute__((address_space(3))) unsigned int*)l, 16, 0, 0);
}

// ---------------------------------------------------------------------------
// Blocks 0..255: Wtbf[o*256+t] = bf16(W[t*256+o]).
// Block 256:     wa[k] = W[k,:]·a_l ; wa[256+k] = W[k,:]·a_r  (fp32).
// ---------------------------------------------------------------------------
__global__ void wt_wa_kernel(const float* __restrict__ W,
                             const float* __restrict__ a,
                             unsigned short* __restrict__ Wtbf,
                             float* __restrict__ wa) {
    const int t = threadIdx.x;
    if (blockIdx.x < 256) {
        const int o = blockIdx.x;
        Wtbf[o * 256 + t] = f2bf(W[t * 256 + o]);
    } else {
        float sl = 0.f, sr = 0.f;
        const float* wr = W + t * 256;
        for (int o = 0; o < 256; ++o) {
            const float wv = wr[o];
            sl += wv * a[o];
            sr += wv * a[256 + o];
        }
        wa[t] = sl;
        wa[256 + t] = sr;
    }
}

// ---------------------------------------------------------------------------
// One wave per row r: el[r] = x[r,:]·wa_l, er[r] = x[r,:]·wa_r,
// and xbf[r,:] = bf16(x[r,:]).
// ---------------------------------------------------------------------------
__global__ __launch_bounds__(256) void eler2x_kernel(
    const float* __restrict__ x, const float* __restrict__ wa,
    float* __restrict__ el, float* __restrict__ er,
    unsigned short* __restrict__ xbf)
{
    const int w = threadIdx.x >> 6, l = threadIdx.x & 63;
    const int r = blockIdx.x * 4 + w;       // 0..16383
    const float4 xv = *(const float4*)(x + (size_t)r * 256 + l * 4);
    const float4 al = *(const float4*)(wa + l * 4);
    const float4 ar = *(const float4*)(wa + 256 + l * 4);

    ushort4 xb;
    xb.x = f2bf(xv.x); xb.y = f2bf(xv.y); xb.z = f2bf(xv.z); xb.w = f2bf(xv.w);
    *(ushort4*)(xbf + (size_t)r * 256 + l * 4) = xb;

    float sl = xv.x * al.x + xv.y * al.y + xv.z * al.z + xv.w * al.w;
    float sr = xv.x * ar.x + xv.y * ar.y + xv.z * ar.z + xv.w * ar.w;
#pragma unroll
    for (int off = 32; off >= 1; off >>= 1) {
        sl += __shfl_xor(sl, off);
        sr += __shfl_xor(sr, off);
    }
    if (l == 0) { el[r] = sl; er[r] = sr; }
}

// ---------------------------------------------------------------------------
// h_T (256 x 16384) = Wtbf (256x256) @ xbf^T.  Flat batched GEMM.
// 64(m) x 128(n) tiles, K-step 64, grid (128,4) = 512 blocks (2/CU).
// LDS XOR-swizzled: chunk (row, cc) stored at row*8 + (cc ^ (row&7));
// the swizzle permutes the GLOBAL source per lane, LDS dest stays linear
// (global_load_lds requires wave-uniform base + lane*16).
// ---------------------------------------------------------------------------
__global__ __launch_bounds__(256) void gemm_h(
    const unsigned short* __restrict__ A,    // Wtbf 256x256
    const unsigned short* __restrict__ Bt,   // xbf 16384x256
    unsigned short* __restrict__ C)          // h_T 256x16384
{
    __shared__ __align__(16) unsigned short As[64 * 64];    //  8 KB
    __shared__ __align__(16) unsigned short Bs[128 * 64];   // 16 KB

    const int tid = threadIdx.x;
    const int w = tid >> 6, l = tid & 63;
    const int q = l >> 4, ml = l & 15;
    const int wm = (w >> 1) * 32;
    const int wn = (w & 1) * 64;
    const int m0 = blockIdx.y * 64;
    const int n0 = blockIdx.x * 128;

    f32x4 acc[2][4];
    for (int i = 0; i < 2; ++i)
        for (int j = 0; j < 4; ++j) {
            f32x4 z = {0.f, 0.f, 0.f, 0.f};
            acc[i][j] = z;
        }

    for (int k0 = 0; k0 < 256; k0 += 64) {
        // As: 64 rows x 8 chunks = 512 chunks, 2 rounds
        for (int c = 0; c < 2; ++c) {
            const int cb = c * 256 + (w << 6);
            const int p = cb + l;
            const int r = p >> 3;
            const int cc = (p & 7) ^ (r & 7);
            gload_lds16(A + (size_t)(m0 + r) * 256 + k0 + cc * 8, As + cb * 8);
        }
        // Bs: 128 rows x 8 chunks = 1024 chunks, 4 rounds
        for (int c = 0; c < 4; ++c) {
            const int cb = c * 256 + (w << 6);
            const int p = cb + l;
            const int r = p >> 3;
            const int cc = (p & 7) ^ (r & 7);
            gload_lds16(Bt + (size_t)(n0 + r) * 256 + k0 + cc * 8, Bs + cb * 8);
        }
        __syncthreads();

        bf16x8 aF[2][2], bF[2][4];
#pragma unroll
        for (int ks = 0; ks < 2; ++ks) {
#pragma unroll
            for (int mt = 0; mt < 2; ++mt) {
                const int mm = wm + mt * 16 + ml;
                aF[ks][mt] = *(const bf16x8*)(As + (mm * 8 + ((ks * 4 + q) ^ (mm & 7))) * 8);
            }
#pragma unroll
            for (int nt = 0; nt < 4; ++nt) {
                const int nn = wn + nt * 16 + ml;
                bF[ks][nt] = *(const bf16x8*)(Bs + (nn * 8 + ((ks * 4 + q) ^ (nn & 7))) * 8);
            }
        }
#pragma unroll
        for (int ks = 0; ks < 2; ++ks)
            for (int mt = 0; mt < 2; ++mt)
                for (int nt = 0; nt < 4; ++nt)
                    acc[mt][nt] = __builtin_amdgcn_mfma_f32_16x16x32_bf16(
                        aF[ks][mt], bF[ks][nt], acc[mt][nt], 0, 0, 0);
        __syncthreads();
    }

    // D layout: col=lane&15, row=(lane>>4)*4+reg
    for (int mt = 0; mt < 2; ++mt)
        for (int nt = 0; nt < 4; ++nt) {
            const int gn = n0 + wn + nt * 16 + ml;
            for (int r = 0; r < 4; ++r) {
                const int gm = m0 + wm + mt * 16 + q * 4 + r;
                C[(size_t)gm * 16384 + gn] = f2bf(acc[mt][nt][r]);
            }
        }
}

// ---------------------------------------------------------------------------
// Mask pre-pass. One wave per row. c[row] = m + log(sum exp(e-m));
// adjacency packed to pk16[row*64 + l] (bit t <-> j = 16*l + t).
// ---------------------------------------------------------------------------
__global__ __launch_bounds__(256) void mask_kernel(
    const int* __restrict__ adj,
    const float* __restrict__ el,
    const float* __restrict__ er,
    float* __restrict__ c,
    unsigned short* __restrict__ pk16)
{
    __shared__ unsigned char nibs[4][256];

    const int w = threadIdx.x >> 6, l = threadIdx.x & 63;
    const int row = blockIdx.x * 4 + w;       // 0..16383
    const int b = row >> 10;
    const int* arow = adj + (size_t)row * 1024;
    const float* erb = er + (b << 10);
    const float eli = el[row];

    float ev[16];
    float m = -3.0e38f;
#pragma unroll
    for (int it = 0; it < 4; ++it) {
        const int j = it * 256 + l * 4;
        const int4 av = *(const int4*)(arow + j);
        const float4 erv = *(const float4*)(erb + j);
        float e0 = eli + erv.x; e0 = e0 > 0.f ? e0 : ALPHA * e0; e0 = av.x > 0 ? e0 : NEG_BIG;
        float e1 = eli + erv.y; e1 = e1 > 0.f ? e1 : ALPHA * e1; e1 = av.y > 0 ? e1 : NEG_BIG;
        float e2 = eli + erv.z; e2 = e2 > 0.f ? e2 : ALPHA * e2; e2 = av.z > 0 ? e2 : NEG_BIG;
        float e3 = eli + erv.w; e3 = e3 > 0.f ? e3 : ALPHA * e3; e3 = av.w > 0 ? e3 : NEG_BIG;
        ev[it * 4 + 0] = e0; ev[it * 4 + 1] = e1;
        ev[it * 4 + 2] = e2; ev[it * 4 + 3] = e3;
        m = fmaxf(m, fmaxf(fmaxf(e0, e1), fmaxf(e2, e3)));
        nibs[w][it * 64 + l] =
            (unsigned char)((av.x > 0) | ((av.y > 0) << 1) |
                            ((av.z > 0) << 2) | ((av.w > 0) << 3));
    }
#pragma unroll
    for (int off = 32; off >= 1; off >>= 1) m = fmaxf(m, __shfl_xor(m, off));
    float s = 0.f;
#pragma unroll
    for (int u = 0; u < 16; ++u) s += __expf(ev[u] - m);
#pragma unroll
    for (int off = 32; off >= 1; off >>= 1) s += __shfl_xor(s, off);
    if (l == 0) c[row] = m + __logf(s);

    const unsigned nr = *(const unsigned int*)(&nibs[w][l * 4]);
    const unsigned short mask16 =
        (unsigned short)((nr & 0xFu) | ((nr >> 4) & 0xF0u) |
                         ((nr >> 8) & 0xF00u) | ((nr >> 12) & 0xF000u));
    pk16[(size_t)row * 64 + l] = mask16;
}

// ---------------------------------------------------------------------------
// PV: out[b, i0..i0+31, :] = P @ h[b].  Grid (32,16) = 512 blocks (2/CU).
// j-step 64: 16 iters, 16 MFMA/wave/iter.  Hs (256 o-rows x 64 j) is
// XOR-swizzled (2-way, free); Ps (32 x 64) padded to stride 72.
// ---------------------------------------------------------------------------
__global__ __launch_bounds__(256) void pv_kernel(
    const unsigned short* __restrict__ pk16,
    const float* __restrict__ el,
    const float* __restrict__ er,
    const float* __restrict__ c,
    const unsigned short* __restrict__ hT,   // 256 x 16384 (row stride 16384)
    float* __restrict__ out)
{
    __shared__ float er_s[1024];
    __shared__ __align__(16) unsigned short pk_s[32 * 64];
    __shared__ __align__(16) unsigned short Hs[256 * 64];   // 32 KB, swizzled
    __shared__ __align__(16) unsigned short Ps[32 * 72];    // pad: 2-way only

    const int tid = threadIdx.x;
    const int w = tid >> 6, l = tid & 63;
    const int q = l >> 4, ml = l & 15;
    const int b = blockIdx.y;
    const int i0 = blockIdx.x * 32;

    *(float4*)(er_s + tid * 4) = *(const float4*)(er + (b << 10) + tid * 4);
    *(u16x8*)(pk_s + tid * 8) =
        *(const u16x8*)(pk16 + ((size_t)(b << 10) + i0) * 64 + tid * 8);
    const int ib = tid >> 3;              // P-row this thread rebuilds (0..31)
    const int js = (tid & 7) * 8;         // j-offset within 64-chunk
    const float eli_b = el[(b << 10) + i0 + ib];
    const float ci = c[(b << 10) + i0 + ib];
    __syncthreads();

    f32x4 acc[2][4];
    for (int i = 0; i < 2; ++i)
        for (int j = 0; j < 4; ++j) {
            f32x4 z = {0.f, 0.f, 0.f, 0.f};
            acc[i][j] = z;
        }

    const unsigned short* hb = hT + (size_t)b * 1024;

    for (int j0 = 0; j0 < 1024; j0 += 64) {
        // stage Hs: 256 rows x 8 chunks = 2048 chunks, 8 rounds
        for (int cr = 0; cr < 8; ++cr) {
            const int cb = cr * 256 + (w << 6);
            const int p = cb + l;
            const int r = p >> 3;
            const int cc = (p & 7) ^ (r & 7);
            gload_lds16(hb + (size_t)r * 16384 + j0 + cc * 8, Hs + cb * 8);
        }
        // build P tile (32 x 64) while loads fly: thread -> row ib, cols js..js+7
        {
            const unsigned hw = pk_s[ib * 64 + ((j0 + js) >> 4)];
            const unsigned v = (hw >> ((j0 + js) & 15)) & 0xFFu;   // sh is 0 or 8
            u16x8 pvv;
#pragma unroll
            for (int u = 0; u < 8; ++u) {
                float e = eli_b + er_s[j0 + js + u];
                e = e > 0.f ? e : ALPHA * e;
                const float p = ((v >> u) & 1u) ? __expf(e - ci) : 0.f;
                pvv[u] = f2bf(p);
            }
            *(u16x8*)(Ps + ib * 72 + js) = pvv;
        }
        __syncthreads();

        bf16x8 aF[2][2], bF[2][4];
#pragma unroll
        for (int ks = 0; ks < 2; ++ks) {
#pragma unroll
            for (int mt = 0; mt < 2; ++mt)
                aF[ks][mt] = *(const bf16x8*)(Ps + (mt * 16 + ml) * 72 + ks * 32 + q * 8);
#pragma unroll
            for (int nt = 0; nt < 4; ++nt) {
                const int oc = (w << 6) + nt * 16 + ml;
                bF[ks][nt] = *(const bf16x8*)(Hs + (oc * 8 + ((ks * 4 + q) ^ (oc & 7))) * 8);
            }
        }
#pragma unroll
        for (int ks = 0; ks < 2; ++ks)
            for (int mt = 0; mt < 2; ++mt)
                for (int nt = 0; nt < 4; ++nt)
                    acc[mt][nt] = __builtin_amdgcn_mfma_f32_16x16x32_bf16(
                        aF[ks][mt], bF[ks][nt], acc[mt][nt], 0, 0, 0);
        __syncthreads();
    }

    float* ob = out + (size_t)b * 262144;
    for (int mt = 0; mt < 2; ++mt)
        for (int nt = 0; nt < 4; ++nt) {
            const int gn = (w << 6) + nt * 16 + ml;
            for (int r = 0; r < 4; ++r) {
                const int gm = i0 + mt * 16 + q * 4 + r;
                ob[(size_t)gm * 256 + gn] = acc[mt][nt][r];
            }
        }
}

// ---------------------------------------------------------------------------
// Workspace (~19.2 MB):
//   Wtbf (bf16) @ 0        : 131072
//   wa   (f32)  @ 131072   : 2048
//   xbf  (bf16) @ 133120   : 8388608   (16384 x 256)
//   h_T  (bf16) @ 8521728  : 8388608   (256 x 16384)
//   el   (f32)  @ 16910336 : 65536
//   er   (f32)  @ 16975872 : 65536
//   c    (f32)  @ 17041408 : 65536
//   pk16 (u16)  @ 17106944 : 2097152
// ---------------------------------------------------------------------------
extern "C" void kernel_launch(void* const* d_in, const int* in_sizes, int n_in,
                              void* d_out, int out_size, void* d_ws, size_t ws_size,
                              hipStream_t stream) {
    const float* x   = (const float*)d_in[0];   // (16,1024,256) fp32
    const int*   adj = (const int*)d_in[1];     // (16,1024,1024) int32
    const float* W   = (const float*)d_in[2];   // (256,256) fp32
    const float* a   = (const float*)d_in[3];   // (512,1) fp32
    float* out = (float*)d_out;                 // (16,1024,256) fp32

    char* ws = (char*)d_ws;
    unsigned short* Wtbf  = (unsigned short*)(ws);
    float* wa             = (float*)(ws + 131072);
    unsigned short* xbf   = (unsigned short*)(ws + 133120);
    unsigned short* h_T   = (unsigned short*)(ws + 8521728);
    float* el             = (float*)(ws + 16910336);
    float* er             = (float*)(ws + 16975872);
    float* c              = (float*)(ws + 17041408);
    unsigned short* pk16  = (unsigned short*)(ws + 17106944);

    wt_wa_kernel<<<dim3(257), dim3(256), 0, stream>>>(W, a, Wtbf, wa);

    eler2x_kernel<<<dim3(4096), dim3(256), 0, stream>>>(x, wa, el, er, xbf);

    // h_T (256 x 16384) = Wtbf @ xbf^T
    gemm_h<<<dim3(128, 4), dim3(256), 0, stream>>>(Wtbf, xbf, h_T);

    mask_kernel<<<dim3(4096), dim3(256), 0, stream>>>(adj, el, er, c, pk16);

    pv_kernel<<<dim3(32, 16), dim3(256), 0, stream>>>(pk16, el, er, c, h_T, out);
}